// Round 5
// baseline (471.408 us; speedup 1.0000x reference)
//
#include <hip/hip_runtime.h>
#include <math.h>

#define NROWS 8192
#define DDIM  512
#define NTRIP 200000
#define CHUNK 8          // triplets per work unit (load-balance quantum)
#define MAXCH 8          // bincap / CHUNK

typedef __attribute__((ext_vector_type(8))) _Float16 half8;
typedef __attribute__((ext_vector_type(4))) _Float16 half4;
typedef __attribute__((ext_vector_type(2))) _Float16 half2v;

__device__ __forceinline__ float wave_sum_all(float v) {
    #pragma unroll
    for (int off = 32; off > 0; off >>= 1) v += __shfl_xor(v, off, 64);
    return v;
}

__device__ __forceinline__ float dot8(const half8 a, const half8 b, float acc) {
#if __has_builtin(__builtin_amdgcn_fdot2)
    acc = __builtin_amdgcn_fdot2((half2v){a[0],a[1]}, (half2v){b[0],b[1]}, acc, false);
    acc = __builtin_amdgcn_fdot2((half2v){a[2],a[3]}, (half2v){b[2],b[3]}, acc, false);
    acc = __builtin_amdgcn_fdot2((half2v){a[4],a[5]}, (half2v){b[4],b[5]}, acc, false);
    acc = __builtin_amdgcn_fdot2((half2v){a[6],a[7]}, (half2v){b[6],b[7]}, acc, false);
    return acc;
#else
    #pragma unroll
    for (int e = 0; e < 8; ++e) acc += (float)a[e] * (float)b[e];
    return acc;
#endif
}

// softplus(z) = max(z,0) + log1p(exp(-|z|)), with hardware exp/log.
// For large |z| __expf underflows to 0 -> __logf(1)=0: correct tail.
__device__ __forceinline__ float softplus_fast(float z) {
    return fmaxf(z, 0.0f) + __logf(1.0f + __expf(-fabsf(z)));
}

// Zero the bin counters and the output accumulator (one dispatch).
__global__ __launch_bounds__(256) void zero_kernel(int* __restrict__ count,
                                                   float* __restrict__ out) {
    const int t = blockIdx.x * 256 + threadIdx.x;
    if (t < NROWS) count[t] = 0;
    if (t == 0) out[0] = 0.0f;
}

// One WAVE per row (4 rows per 256-block) + fused triplet scatter.
__global__ __launch_bounds__(256) void prep_kernel(
    const float* __restrict__ x, const float* __restrict__ y,
    const float* __restrict__ norm_s,
    const int* __restrict__ trip, int* __restrict__ count,
    int2* __restrict__ slots,
    _Float16* __restrict__ xh, _Float16* __restrict__ yh,
    float2* __restrict__ sq)
{
    // ---- scatter: bucket this thread's triplet by i ----
    const int tid = blockIdx.x * 256 + threadIdx.x;
    if (tid < NTRIP) {
        const int i = trip[3*tid], j = trip[3*tid+1], k = trip[3*tid+2];
        const int c = atomicAdd(&count[i], 1);
        if (c < CHUNK * MAXCH) slots[((size_t)i << 6) + c] = (int2){j, k};
    }

    // ---- row prep: fp32 -> fp16, y normalization, rounded sq-norms ----
    const int row  = blockIdx.x * 4 + (threadIdx.x >> 6);
    const int lane = threadIdx.x & 63;
    const float4* xr = (const float4*)(x + (size_t)row * DDIM);
    const float4* yr = (const float4*)(y + (size_t)row * DDIM);
    const float4 x0 = xr[lane], x1 = xr[lane + 64];
    const float4 y0 = yr[lane], y1 = yr[lane + 64];

    float sy = y0.x*y0.x + y0.y*y0.y + y0.z*y0.z + y0.w*y0.w
             + y1.x*y1.x + y1.y*y1.y + y1.z*y1.z + y1.w*y1.w;
    sy = wave_sum_all(sy);
    const float scale = norm_s[0] / sqrtf(sy);

    const half4 hx0 = {(_Float16)x0.x, (_Float16)x0.y, (_Float16)x0.z, (_Float16)x0.w};
    const half4 hx1 = {(_Float16)x1.x, (_Float16)x1.y, (_Float16)x1.z, (_Float16)x1.w};
    const half4 hy0 = {(_Float16)(y0.x*scale), (_Float16)(y0.y*scale),
                       (_Float16)(y0.z*scale), (_Float16)(y0.w*scale)};
    const half4 hy1 = {(_Float16)(y1.x*scale), (_Float16)(y1.y*scale),
                       (_Float16)(y1.z*scale), (_Float16)(y1.w*scale)};

    // sq-norms of the ROUNDED values so i==j distances cancel before the clamp
    float sx = 0.f, sqy = 0.f;
    #pragma unroll
    for (int e = 0; e < 4; ++e) {
        sx  += (float)hx0[e]*(float)hx0[e] + (float)hx1[e]*(float)hx1[e];
        sqy += (float)hy0[e]*(float)hy0[e] + (float)hy1[e]*(float)hy1[e];
    }
    sx  = wave_sum_all(sx);
    sqy = wave_sum_all(sqy);

    ((half4*)(xh + (size_t)row * DDIM))[lane]      = hx0;
    ((half4*)(xh + (size_t)row * DDIM))[lane + 64] = hx1;
    ((half4*)(yh + (size_t)row * DDIM))[lane]      = hy0;
    ((half4*)(yh + (size_t)row * DDIM))[lane + 64] = hy1;
    if (lane == 0) sq[row] = (float2){sx, sqy};
}

// One wave per (bin, chunk-of-8). 4 groups of 16 lanes: g0:x_j g1:x_k
// g2:y_j g3:y_k. All 4 dots of a triplet reduce simultaneously in one
// 4-level butterfly; transposed epilogue (img z in g0, txt z in g2).
__global__ __launch_bounds__(256) void trip_kernel(
    const _Float16* __restrict__ xh, const _Float16* __restrict__ yh,
    const float2* __restrict__ sq, const int* __restrict__ count,
    const int2* __restrict__ slots, float* __restrict__ out)
{
    const int lane = threadIdx.x & 63;
    const int wid  = blockIdx.x * 4 + (threadIdx.x >> 6);
    const int c    = wid >> 13;          // chunk index (chunk-major order)
    const int bin  = wid & (NROWS - 1);  // == i

    int n = count[bin];
    n = __builtin_amdgcn_readfirstlane(n < CHUNK * MAXCH ? n : CHUNK * MAXCH);
    const int t0 = c * CHUNK;
    int m = n - t0;                      // triplets in this chunk
    if (m <= 0) return;
    if (m > CHUNK) m = CHUNK;

    const int  s     = lane & 15;          // slice within row
    const bool isK   = (lane & 16) != 0;   // groups 1,3 -> k-row
    const bool isTxt = (lane & 32) != 0;   // groups 2,3 -> y
    const _Float16* base = isTxt ? yh : xh;

    const half8* irow = ((const half8*)(base + (size_t)bin * DDIM)) + (s << 2);
    const half8 ci0 = irow[0], ci1 = irow[1], ci2 = irow[2], ci3 = irow[3];

    const float2 sqi = sq[bin];
    const float sq_self = isTxt ? sqi.y : sqi.x;

    const int2* bs = slots + ((size_t)bin << 6) + t0;
    float acc = 0.0f;
    int t = 0;

    for (; t + 4 <= m; t += 4) {
        int jj[4], kk[4];
        #pragma unroll
        for (int u = 0; u < 4; ++u) {
            const int2 p = bs[t + u];
            jj[u] = __builtin_amdgcn_readfirstlane(p.x);
            kk[u] = __builtin_amdgcn_readfirstlane(p.y);
        }
        half8 rv[4][4];
        #pragma unroll
        for (int u = 0; u < 4; ++u) {
            const int r = isK ? kk[u] : jj[u];
            const half8* rp = ((const half8*)(base + (size_t)r * DDIM)) + (s << 2);
            rv[u][0] = rp[0]; rv[u][1] = rp[1]; rv[u][2] = rp[2]; rv[u][3] = rp[3];
        }
        float sq_r[4];
        #pragma unroll
        for (int u = 0; u < 4; ++u) {
            const float2 sqj = sq[jj[u]];
            const float2 sqk = sq[kk[u]];
            sq_r[u] = isTxt ? (isK ? sqk.y : sqj.y) : (isK ? sqk.x : sqj.x);
        }
        float dist[4];
        #pragma unroll
        for (int u = 0; u < 4; ++u) {
            float p = dot8(ci0, rv[u][0], 0.0f);
            p = dot8(ci1, rv[u][1], p);
            p = dot8(ci2, rv[u][2], p);
            p = dot8(ci3, rv[u][3], p);
            #pragma unroll
            for (int off = 1; off < 16; off <<= 1) p += __shfl_xor(p, off, 64);
            dist[u] = fmaxf(sq_self + sq_r[u] - 2.0f * p, 0.0f);
        }
        #pragma unroll
        for (int u = 0; u < 4; ++u) {
            const float z = dist[u] - __shfl_xor(dist[u], 16, 64);
            acc += isK ? 0.0f : softplus_fast(z);  // groups 0 (img), 2 (txt)
        }
    }
    for (; t < m; ++t) {  // tail, <=3 iterations
        const int2 p0 = bs[t];
        const int j0 = __builtin_amdgcn_readfirstlane(p0.x);
        const int k0 = __builtin_amdgcn_readfirstlane(p0.y);
        const int r = isK ? k0 : j0;
        const half8* rp = ((const half8*)(base + (size_t)r * DDIM)) + (s << 2);
        float p = dot8(ci0, rp[0], 0.0f);
        p = dot8(ci1, rp[1], p);
        p = dot8(ci2, rp[2], p);
        p = dot8(ci3, rp[3], p);
        #pragma unroll
        for (int off = 1; off < 16; off <<= 1) p += __shfl_xor(p, off, 64);
        const float2 sqj = sq[j0];
        const float2 sqk = sq[k0];
        const float sq_r = isTxt ? (isK ? sqk.y : sqj.y) : (isK ? sqk.x : sqj.x);
        const float dist = fmaxf(sq_self + sq_r - 2.0f * p, 0.0f);
        const float z = dist - __shfl_xor(dist, 16, 64);
        acc += isK ? 0.0f : softplus_fast(z);
    }

    // groups 0/2 each hold 16 identical copies -> divide by 16
    acc = wave_sum_all(acc);
    if (lane == 0) atomicAdd(out, acc * (1.0f / (16.0f * (float)NTRIP)));
}

extern "C" void kernel_launch(void* const* d_in, const int* in_sizes, int n_in,
                              void* d_out, int out_size, void* d_ws, size_t ws_size,
                              hipStream_t stream) {
    const float* x      = (const float*)d_in[0];
    const float* y      = (const float*)d_in[1];
    const float* norm_s = (const float*)d_in[2];
    const int*   trip   = (const int*)d_in[3];

    _Float16* xh    = (_Float16*)d_ws;                          // 8 MB
    _Float16* yh    = xh + (size_t)NROWS * DDIM;                // 8 MB
    float2*   sq    = (float2*)(yh + (size_t)NROWS * DDIM);     // 64 KB
    int*      count = (int*)(sq + NROWS);                       // 32 KB
    int2*     slots = (int2*)(count + NROWS);                   // NROWS*64*8 B = 4 MB

    zero_kernel<<<NROWS / 256, 256, 0, stream>>>(count, (float*)d_out);
    prep_kernel<<<NROWS / 4, 256, 0, stream>>>(x, y, norm_s, trip, count, slots,
                                               xh, yh, sq);
    // NROWS * MAXCH chunks, 4 waves per block; chunk-major so non-empty
    // chunks cluster at the front of the grid.
    trip_kernel<<<NROWS * MAXCH / 4, 256, 0, stream>>>(xh, yh, sq, count, slots,
                                                       (float*)d_out);
}

// Round 6
// 186.051 us; speedup vs baseline: 2.5338x; 2.5338x over previous
//
#include <hip/hip_runtime.h>
#include <math.h>

#define NROWS 8192
#define DDIM  512
#define NTRIP 200000
#define CHUNK 16         // triplets per work unit (load-balance quantum)
#define MAXCH 4          // bincap / CHUNK
#define NWAVE (NROWS * MAXCH)   // 32768 work units / partial slots

typedef __attribute__((ext_vector_type(8))) _Float16 half8;
typedef __attribute__((ext_vector_type(4))) _Float16 half4;
typedef __attribute__((ext_vector_type(2))) _Float16 half2v;

__device__ __forceinline__ float wave_sum_all(float v) {
    #pragma unroll
    for (int off = 32; off > 0; off >>= 1) v += __shfl_xor(v, off, 64);
    return v;
}

__device__ __forceinline__ float dot8(const half8 a, const half8 b, float acc) {
#if __has_builtin(__builtin_amdgcn_fdot2)
    acc = __builtin_amdgcn_fdot2((half2v){a[0],a[1]}, (half2v){b[0],b[1]}, acc, false);
    acc = __builtin_amdgcn_fdot2((half2v){a[2],a[3]}, (half2v){b[2],b[3]}, acc, false);
    acc = __builtin_amdgcn_fdot2((half2v){a[4],a[5]}, (half2v){b[4],b[5]}, acc, false);
    acc = __builtin_amdgcn_fdot2((half2v){a[6],a[7]}, (half2v){b[6],b[7]}, acc, false);
    return acc;
#else
    #pragma unroll
    for (int e = 0; e < 8; ++e) acc += (float)a[e] * (float)b[e];
    return acc;
#endif
}

// softplus(z) = max(z,0) + log1p(exp(-|z|)), hardware exp/log.
__device__ __forceinline__ float softplus_fast(float z) {
    return fmaxf(z, 0.0f) + __logf(1.0f + __expf(-fabsf(z)));
}

// Zero bin counters, per-wave partials, and the output (one dispatch).
__global__ __launch_bounds__(256) void zero_kernel(int* __restrict__ count,
                                                   float* __restrict__ partial,
                                                   float* __restrict__ out) {
    const int t = blockIdx.x * 256 + threadIdx.x;
    if (t < NWAVE) partial[t] = 0.0f;
    if (t < NROWS) count[t] = 0;
    if (t == 0) out[0] = 0.0f;
}

// One WAVE per row (4 rows per 256-block) + fused triplet scatter.
__global__ __launch_bounds__(256) void prep_kernel(
    const float* __restrict__ x, const float* __restrict__ y,
    const float* __restrict__ norm_s,
    const int* __restrict__ trip, int* __restrict__ count,
    int2* __restrict__ slots,
    _Float16* __restrict__ xh, _Float16* __restrict__ yh,
    float2* __restrict__ sq)
{
    // ---- scatter: bucket this thread's triplet by i ----
    const int tid = blockIdx.x * 256 + threadIdx.x;
    if (tid < NTRIP) {
        const int i = trip[3*tid], j = trip[3*tid+1], k = trip[3*tid+2];
        const int c = atomicAdd(&count[i], 1);   // 200k atomics over 8192 addrs: fine
        if (c < CHUNK * MAXCH) slots[((size_t)i << 6) + c] = (int2){j, k};
    }

    // ---- row prep: fp32 -> fp16, y normalization, rounded sq-norms ----
    const int row  = blockIdx.x * 4 + (threadIdx.x >> 6);
    const int lane = threadIdx.x & 63;
    const float4* xr = (const float4*)(x + (size_t)row * DDIM);
    const float4* yr = (const float4*)(y + (size_t)row * DDIM);
    const float4 x0 = xr[lane], x1 = xr[lane + 64];
    const float4 y0 = yr[lane], y1 = yr[lane + 64];

    float sy = y0.x*y0.x + y0.y*y0.y + y0.z*y0.z + y0.w*y0.w
             + y1.x*y1.x + y1.y*y1.y + y1.z*y1.z + y1.w*y1.w;
    sy = wave_sum_all(sy);
    const float scale = norm_s[0] / sqrtf(sy);

    const half4 hx0 = {(_Float16)x0.x, (_Float16)x0.y, (_Float16)x0.z, (_Float16)x0.w};
    const half4 hx1 = {(_Float16)x1.x, (_Float16)x1.y, (_Float16)x1.z, (_Float16)x1.w};
    const half4 hy0 = {(_Float16)(y0.x*scale), (_Float16)(y0.y*scale),
                       (_Float16)(y0.z*scale), (_Float16)(y0.w*scale)};
    const half4 hy1 = {(_Float16)(y1.x*scale), (_Float16)(y1.y*scale),
                       (_Float16)(y1.z*scale), (_Float16)(y1.w*scale)};

    // sq-norms of the ROUNDED values so i==j distances cancel before the clamp
    float sx = 0.f, sqy = 0.f;
    #pragma unroll
    for (int e = 0; e < 4; ++e) {
        sx  += (float)hx0[e]*(float)hx0[e] + (float)hx1[e]*(float)hx1[e];
        sqy += (float)hy0[e]*(float)hy0[e] + (float)hy1[e]*(float)hy1[e];
    }
    sx  = wave_sum_all(sx);
    sqy = wave_sum_all(sqy);

    ((half4*)(xh + (size_t)row * DDIM))[lane]      = hx0;
    ((half4*)(xh + (size_t)row * DDIM))[lane + 64] = hx1;
    ((half4*)(yh + (size_t)row * DDIM))[lane]      = hy0;
    ((half4*)(yh + (size_t)row * DDIM))[lane + 64] = hy1;
    if (lane == 0) sq[row] = (float2){sx, sqy};
}

// One wave per (bin, chunk-of-16). 4 groups of 16 lanes: g0:x_j g1:x_k
// g2:y_j g3:y_k. All 4 dots of a triplet reduce simultaneously in one
// 4-level butterfly; transposed epilogue (img z in g0, txt z in g2).
// NO contended atomics: wave stores its partial to a unique slot.
__global__ __launch_bounds__(256) void trip_kernel(
    const _Float16* __restrict__ xh, const _Float16* __restrict__ yh,
    const float2* __restrict__ sq, const int* __restrict__ count,
    const int2* __restrict__ slots, float* __restrict__ partial)
{
    const int lane = threadIdx.x & 63;
    const int wid  = blockIdx.x * 4 + (threadIdx.x >> 6);
    const int c    = wid >> 13;          // chunk index (chunk-major order)
    const int bin  = wid & (NROWS - 1);  // == i

    int n = count[bin];
    n = __builtin_amdgcn_readfirstlane(n < CHUNK * MAXCH ? n : CHUNK * MAXCH);
    const int t0 = c * CHUNK;
    int m = n - t0;                      // triplets in this chunk
    if (m <= 0) return;                  // partial[wid] stays 0
    if (m > CHUNK) m = CHUNK;

    const int  s     = lane & 15;          // slice within row
    const bool isK   = (lane & 16) != 0;   // groups 1,3 -> k-row
    const bool isTxt = (lane & 32) != 0;   // groups 2,3 -> y
    const _Float16* base = isTxt ? yh : xh;

    const half8* irow = ((const half8*)(base + (size_t)bin * DDIM)) + (s << 2);
    const half8 ci0 = irow[0], ci1 = irow[1], ci2 = irow[2], ci3 = irow[3];

    const float2 sqi = sq[bin];
    const float sq_self = isTxt ? sqi.y : sqi.x;

    const int2* bs = slots + ((size_t)bin << 6) + t0;
    float acc = 0.0f;
    int t = 0;

    for (; t + 4 <= m; t += 4) {
        int jj[4], kk[4];
        #pragma unroll
        for (int u = 0; u < 4; ++u) {
            const int2 p = bs[t + u];
            jj[u] = __builtin_amdgcn_readfirstlane(p.x);
            kk[u] = __builtin_amdgcn_readfirstlane(p.y);
        }
        half8 rv[4][4];
        #pragma unroll
        for (int u = 0; u < 4; ++u) {
            const int r = isK ? kk[u] : jj[u];
            const half8* rp = ((const half8*)(base + (size_t)r * DDIM)) + (s << 2);
            rv[u][0] = rp[0]; rv[u][1] = rp[1]; rv[u][2] = rp[2]; rv[u][3] = rp[3];
        }
        float sq_r[4];
        #pragma unroll
        for (int u = 0; u < 4; ++u) {
            const float2 sqj = sq[jj[u]];
            const float2 sqk = sq[kk[u]];
            sq_r[u] = isTxt ? (isK ? sqk.y : sqj.y) : (isK ? sqk.x : sqj.x);
        }
        float dist[4];
        #pragma unroll
        for (int u = 0; u < 4; ++u) {
            float p = dot8(ci0, rv[u][0], 0.0f);
            p = dot8(ci1, rv[u][1], p);
            p = dot8(ci2, rv[u][2], p);
            p = dot8(ci3, rv[u][3], p);
            #pragma unroll
            for (int off = 1; off < 16; off <<= 1) p += __shfl_xor(p, off, 64);
            dist[u] = fmaxf(sq_self + sq_r[u] - 2.0f * p, 0.0f);
        }
        #pragma unroll
        for (int u = 0; u < 4; ++u) {
            const float z = dist[u] - __shfl_xor(dist[u], 16, 64);
            acc += isK ? 0.0f : softplus_fast(z);  // groups 0 (img), 2 (txt)
        }
    }
    for (; t < m; ++t) {  // tail, <=3 iterations
        const int2 p0 = bs[t];
        const int j0 = __builtin_amdgcn_readfirstlane(p0.x);
        const int k0 = __builtin_amdgcn_readfirstlane(p0.y);
        const int r = isK ? k0 : j0;
        const half8* rp = ((const half8*)(base + (size_t)r * DDIM)) + (s << 2);
        float p = dot8(ci0, rp[0], 0.0f);
        p = dot8(ci1, rp[1], p);
        p = dot8(ci2, rp[2], p);
        p = dot8(ci3, rp[3], p);
        #pragma unroll
        for (int off = 1; off < 16; off <<= 1) p += __shfl_xor(p, off, 64);
        const float2 sqj = sq[j0];
        const float2 sqk = sq[k0];
        const float sq_r = isTxt ? (isK ? sqk.y : sqj.y) : (isK ? sqk.x : sqj.x);
        const float dist = fmaxf(sq_self + sq_r - 2.0f * p, 0.0f);
        const float z = dist - __shfl_xor(dist, 16, 64);
        acc += isK ? 0.0f : softplus_fast(z);
    }

    // wave total = 16*(img_sum + txt_sum); scale applied in reduce_kernel
    acc = wave_sum_all(acc);
    if (lane == 0) partial[wid] = acc;
}

// 32 blocks x 256 threads: one float4 per thread covers all 32768 partials.
// Only 32 atomics total (one per block) -> no serialization.
__global__ __launch_bounds__(256) void reduce_kernel(
    const float* __restrict__ partial, float* __restrict__ out)
{
    const int idx = blockIdx.x * 256 + threadIdx.x;
    const float4 v = ((const float4*)partial)[idx];
    float s = (v.x + v.y) + (v.z + v.w);
    s = wave_sum_all(s);
    __shared__ float red[4];
    const int wv = threadIdx.x >> 6, lane = threadIdx.x & 63;
    if (lane == 0) red[wv] = s;
    __syncthreads();
    if (threadIdx.x == 0) {
        const float blocksum = red[0] + red[1] + red[2] + red[3];
        atomicAdd(out, blocksum * (1.0f / (16.0f * (float)NTRIP)));
    }
}

extern "C" void kernel_launch(void* const* d_in, const int* in_sizes, int n_in,
                              void* d_out, int out_size, void* d_ws, size_t ws_size,
                              hipStream_t stream) {
    const float* x      = (const float*)d_in[0];
    const float* y      = (const float*)d_in[1];
    const float* norm_s = (const float*)d_in[2];
    const int*   trip   = (const int*)d_in[3];

    _Float16* xh      = (_Float16*)d_ws;                        // 8 MB
    _Float16* yh      = xh + (size_t)NROWS * DDIM;              // 8 MB
    float2*   sq      = (float2*)(yh + (size_t)NROWS * DDIM);   // 64 KB
    int*      count   = (int*)(sq + NROWS);                     // 32 KB
    float*    partial = (float*)(count + NROWS);                // 128 KB
    int2*     slots   = (int2*)(partial + NWAVE);               // 4 MB

    zero_kernel<<<NWAVE / 256, 256, 0, stream>>>(count, partial, (float*)d_out);
    prep_kernel<<<NROWS / 4, 256, 0, stream>>>(x, y, norm_s, trip, count, slots,
                                               xh, yh, sq);
    trip_kernel<<<NWAVE / 4, 256, 0, stream>>>(xh, yh, sq, count, slots, partial);
    reduce_kernel<<<NWAVE / 4 / 256, 256, 0, stream>>>(partial, (float*)d_out);
}